// Round 2
// baseline (549.329 us; speedup 1.0000x reference)
//
#include <hip/hip_runtime.h>

// AdaptiveSparseUpdateRule round 2: barrier-free per-wave design.
// prep_weights packs W1/W2/W3 into bf16 A-operand fragments (transposed MLP:
// H^T = W^T @ X^T) in d_ws. Main kernel: 512 blocks x 4 waves, each wave
// independently processes 8 tiles of 64 pixels; weights in VGPRs; per-wave
// private LDS for feature/H1/H2 round-trips; NO __syncthreads anywhere.

#define TPB 256
#define WAVES_PER_BLOCK 4
#define NBLOCKS 512
#define NTILES 16384                        // 16 b * 256 h * 4 wt
#define NWAVES (NBLOCKS * WAVES_PER_BLOCK)  // 2048
#define ITERS (NTILES / NWAVES)             // 8

using bf16x8 = __attribute__((ext_vector_type(8))) __bf16;
using f32x4  = __attribute__((ext_vector_type(4))) float;

__device__ __forceinline__ unsigned f2bf(float f) {
    unsigned u = __float_as_uint(f);
    u += 0x7fffu + ((u >> 16) & 1u);   // RNE; inputs finite
    return u >> 16;
}

// ---- ws layout (ushort units) ----
// feature order k = 3*c + t  (t: 0=x, 1=sobel_x, 2=sobel_y), K-padded 48->64
#define WS1_OFF 0        // [mt=8][kb=2][lane=64][8]  A-frags of W1^T
#define WS2_OFF 8192     // [mt=8][kb=4][lane=64][8]  A-frags of W2^T
#define WS3_OFF 24576    // [kb=4][lane=64][8]        A-frags of W3^T

__global__ __launch_bounds__(1024)
void prep_weights(const float* __restrict__ w1, const float* __restrict__ w2,
                  const float* __restrict__ w3, unsigned short* __restrict__ ws) {
    const int s = threadIdx.x;           // 1024 threads, 1 block
    {   // ws1: 1024 slots
        const int mt = s >> 7, kb = (s >> 6) & 1, lane = s & 63;
        const int q = lane >> 4, ln = lane & 15;
#pragma unroll
        for (int j = 0; j < 8; ++j) {
            const int k = kb * 32 + q * 8 + j;
            float val = 0.f;
            if (k < 48) { const int c = k / 3, t = k - 3 * c; val = w1[(t * 16 + c) * 128 + mt * 16 + ln]; }
            ws[WS1_OFF + s * 8 + j] = (unsigned short)f2bf(val);
        }
    }
    for (int s2 = s; s2 < 2048; s2 += 1024) {   // ws2: 2048 slots
        const int mt = s2 >> 8, kb = (s2 >> 6) & 3, lane = s2 & 63;
        const int q = lane >> 4, ln = lane & 15;
#pragma unroll
        for (int j = 0; j < 8; ++j) {
            const int k = kb * 32 + q * 8 + j;
            ws[WS2_OFF + s2 * 8 + j] = (unsigned short)f2bf(w2[k * 128 + mt * 16 + ln]);
        }
    }
    if (s < 256) {   // ws3: 256 slots
        const int kb = s >> 6, lane = s & 63;
        const int q = lane >> 4, ln = lane & 15;
#pragma unroll
        for (int j = 0; j < 8; ++j) {
            const int k = kb * 32 + q * 8 + j;
            ws[WS3_OFF + s * 8 + j] = (unsigned short)f2bf(w3[k * 16 + ln]);
        }
    }
}

// ---- per-wave LDS (bytes) ----
#define FE_STRIDE 144     // 64 px rows x (64 k * 2B) + 16B pad (bank spread)
#define H_STRIDE  272     // 16 px rows x (128 n * 2B) + 16B pad
#define OFF_FE   0        // 64*144 = 9216
#define OFF_H1   9216     // 16*272 = 4352
#define OFF_H2   13568    // 4352
#define OFF_SEL  17920    // 64 f32 = 256
#define PW_LDS   18176
#define LDS_TOTAL (PW_LDS * WAVES_PER_BLOCK)   // 72704

extern "C" __global__ __launch_bounds__(TPB, 2)
void nca_wave(const float* __restrict__ x, const float* __restrict__ fmask,
              const unsigned short* __restrict__ ws,
              const float* __restrict__ b1, const float* __restrict__ b2,
              const float* __restrict__ b3, float* __restrict__ out) {
    extern __shared__ char smem[];
    const int t = threadIdx.x;
    const int wv = t >> 6;
    const int lane = t & 63;
    const int q = lane >> 4, ln = lane & 15;
    char* FE = smem + wv * PW_LDS + OFF_FE;
    char* H1 = smem + wv * PW_LDS + OFF_H1;
    char* H2 = smem + wv * PW_LDS + OFF_H2;
    float* selL = (float*)(smem + wv * PW_LDS + OFF_SEL);

    // ---- weights -> VGPRs (A-operand fragments), once per wave ----
    bf16x8 W1f[8][2], W2f[8][4];
#pragma unroll
    for (int mt = 0; mt < 8; ++mt) {
        W1f[mt][0] = *(const bf16x8*)(ws + WS1_OFF + ((mt * 2 + 0) * 64 + lane) * 8);
        W1f[mt][1] = *(const bf16x8*)(ws + WS1_OFF + ((mt * 2 + 1) * 64 + lane) * 8);
#pragma unroll
        for (int kb = 0; kb < 4; ++kb)
            W2f[mt][kb] = *(const bf16x8*)(ws + WS2_OFF + ((mt * 4 + kb) * 64 + lane) * 8);
    }

    // zero FE K-pad (k = 48..63) once; never rewritten
    {
        char* row = FE + lane * FE_STRIDE;
        *(int4*)(row + 96)  = make_int4(0, 0, 0, 0);
        *(int4*)(row + 112) = make_int4(0, 0, 0, 0);
    }

    const int wave_gid = blockIdx.x * WAVES_PER_BLOCK + wv;
    for (int it = 0; it < ITERS; ++it) {
        const int tile = wave_gid + it * NWAVES;
        const int wt = tile & 3;
        const int h  = (tile >> 2) & 255;
        const int bb = tile >> 10;
        const int w0 = wt * 64;
        const int p  = lane;            // feature-gen: lane = pixel in tile
        const int col = w0 + p;

        // ---- boundary masks (zero-pad conv semantics) + clamped offsets ----
        const float mT = (h > 0) ? 1.f : 0.f;
        const float mB = (h < 255) ? 1.f : 0.f;
        const float mL = (col > 0) ? 1.f : 0.f;
        const float mR = (col < 255) ? 1.f : 0.f;
        const int rT = (h > 0) ? h - 1 : 0;
        const int rB = (h < 255) ? h + 1 : 255;
        const int cLc = (col > 0) ? col - 1 : 0;
        const int cRc = (col < 255) ? col + 1 : 255;
        const int i00 = rT * 256 + cLc, i01 = rT * 256 + col, i02 = rT * 256 + cRc;
        const int i10 = h  * 256 + cLc, i11 = h  * 256 + col, i12 = h  * 256 + cRc;
        const int i20 = rB * 256 + cLc, i21 = rB * 256 + col, i22 = rB * 256 + cRc;
        const float m00 = mT * mL, m01 = mT, m02 = mT * mR;
        const float m20 = mB * mL, m21 = mB, m22 = mB * mR;

        const float* xb = x + ((size_t)bb << 20);    // bb*16*65536

        // ---- features: 16 channels, 2 groups of 8, pack 24 bf16 -> 3x b128 ----
#pragma unroll
        for (int g = 0; g < 2; ++g) {
            unsigned pk[12];
            unsigned carry = 0;
#pragma unroll
            for (int cc = 0; cc < 8; ++cc) {
                const int c = g * 8 + cc;
                const float* xc = xb + ((size_t)c << 16);
                const float v00 = xc[i00] * m00, v01 = xc[i01] * m01, v02 = xc[i02] * m02;
                const float v10 = xc[i10] * mL,  v11 = xc[i11],       v12 = xc[i12] * mR;
                const float v20 = xc[i20] * m20, v21 = xc[i21] * m21, v22 = xc[i22] * m22;
                const float sx = (v02 + 2.f * v12 + v22) - (v00 + 2.f * v10 + v20);
                const float sy = (v20 + 2.f * v21 + v22) - (v00 + 2.f * v01 + v02);
                if (g == 0 && cc == 3) {
                    // alive mask: exact fp32 3x3 maxpool of alpha (zeros-at-border safe: x>=0)
                    float mx = fmaxf(fmaxf(fmaxf(v00, v01), fmaxf(v02, v10)),
                                     fmaxf(fmaxf(v11, v12), fmaxf(fmaxf(v20, v21), v22)));
                    const float fv = fmask[(size_t)(bb * 256 + h) * 256 + col];
                    selL[p] = (fv != 0.f && mx > 0.1f) ? 1.f : 0.f;
                }
                const unsigned ux = f2bf(v11), usx = f2bf(sx), usy = f2bf(sy);
                if ((cc & 1) == 0) { pk[(cc >> 1) * 3] = ux | (usx << 16); carry = usy; }
                else { pk[(cc >> 1) * 3 + 1] = carry | (ux << 16);
                       pk[(cc >> 1) * 3 + 2] = usx | (usy << 16); }
            }
            int4* dst = (int4*)(FE + p * FE_STRIDE + g * 48);
            dst[0] = make_int4(pk[0], pk[1], pk[2],  pk[3]);
            dst[1] = make_int4(pk[4], pk[5], pk[6],  pk[7]);
            dst[2] = make_int4(pk[8], pk[9], pk[10], pk[11]);
        }

        // ---- 4 subtiles of 16 px through the 3 MFMA layers (transposed) ----
        // In-order per-wave DS pipe + may-alias (single smem object) give RAW
        // ordering for the intra-wave LDS round-trips; no barrier needed.
#pragma unroll
        for (int sub = 0; sub < 4; ++sub) {
            const int prow = sub * 16 + ln;
            const bf16x8 B1a = *(const bf16x8*)(FE + prow * FE_STRIDE + q * 16);
            const bf16x8 B1b = *(const bf16x8*)(FE + prow * FE_STRIDE + 64 + q * 16);
            // layer 1: H1^T = relu(W1^T @ F^T + b1)
#pragma unroll
            for (int mt = 0; mt < 8; ++mt) {
                f32x4 acc = *(const f32x4*)(b1 + mt * 16 + q * 4);   // bias = acc init
                acc = __builtin_amdgcn_mfma_f32_16x16x32_bf16(W1f[mt][0], B1a, acc, 0, 0, 0);
                acc = __builtin_amdgcn_mfma_f32_16x16x32_bf16(W1f[mt][1], B1b, acc, 0, 0, 0);
                const unsigned r01 = f2bf(fmaxf(acc[0], 0.f)) | (f2bf(fmaxf(acc[1], 0.f)) << 16);
                const unsigned r23 = f2bf(fmaxf(acc[2], 0.f)) | (f2bf(fmaxf(acc[3], 0.f)) << 16);
                *(uint2*)(H1 + ln * H_STRIDE + mt * 32 + q * 8) = make_uint2(r01, r23);
            }
            bf16x8 B2[4];
#pragma unroll
            for (int kb = 0; kb < 4; ++kb)
                B2[kb] = *(const bf16x8*)(H1 + ln * H_STRIDE + kb * 64 + q * 16);
            // layer 2: H2^T = relu(W2^T @ H1^T + b2)
#pragma unroll
            for (int mt = 0; mt < 8; ++mt) {
                f32x4 acc = *(const f32x4*)(b2 + mt * 16 + q * 4);
#pragma unroll
                for (int kb = 0; kb < 4; ++kb)
                    acc = __builtin_amdgcn_mfma_f32_16x16x32_bf16(W2f[mt][kb], B2[kb], acc, 0, 0, 0);
                const unsigned r01 = f2bf(fmaxf(acc[0], 0.f)) | (f2bf(fmaxf(acc[1], 0.f)) << 16);
                const unsigned r23 = f2bf(fmaxf(acc[2], 0.f)) | (f2bf(fmaxf(acc[3], 0.f)) << 16);
                *(uint2*)(H2 + ln * H_STRIDE + mt * 32 + q * 8) = make_uint2(r01, r23);
            }
            // layer 3: U^T = W3^T @ H2^T + b3  (W3 frags from global, L1-hot)
            f32x4 acc3 = *(const f32x4*)(b3 + q * 4);
#pragma unroll
            for (int kb = 0; kb < 4; ++kb) {
                const bf16x8 W3f = *(const bf16x8*)(ws + WS3_OFF + (kb * 64 + lane) * 8);
                const bf16x8 B3  = *(const bf16x8*)(H2 + ln * H_STRIDE + kb * 64 + q * 16);
                acc3 = __builtin_amdgcn_mfma_f32_16x16x32_bf16(W3f, B3, acc3, 0, 0, 0);
            }
            // epilogue: mask + store (lane holds pixel ln, channels q*4+r)
            const float sv = selL[prow];
            const int wcol = w0 + sub * 16 + ln;
            float* ob = out + ((size_t)bb << 20) + ((size_t)(q * 4) << 16) + (h << 8) + wcol;
#pragma unroll
            for (int r = 0; r < 4; ++r)
                ob[(size_t)r << 16] = acc3[r] * sv;
        }
    }
}

extern "C" void kernel_launch(void* const* d_in, const int* in_sizes, int n_in,
                              void* d_out, int out_size, void* d_ws, size_t ws_size,
                              hipStream_t stream) {
    (void)in_sizes; (void)n_in; (void)out_size; (void)ws_size;
    const float* x  = (const float*)d_in[0];
    const float* fm = (const float*)d_in[1];
    const float* w1 = (const float*)d_in[2];
    const float* b1 = (const float*)d_in[3];
    const float* w2 = (const float*)d_in[4];
    const float* b2 = (const float*)d_in[5];
    const float* w3 = (const float*)d_in[6];
    const float* b3 = (const float*)d_in[7];
    float* o = (float*)d_out;
    unsigned short* ws = (unsigned short*)d_ws;

    prep_weights<<<dim3(1), dim3(1024), 0, stream>>>(w1, w2, w3, ws);

    hipFuncSetAttribute((const void*)nca_wave,
                        hipFuncAttributeMaxDynamicSharedMemorySize, LDS_TOTAL);
    nca_wave<<<dim3(NBLOCKS), dim3(TPB), LDS_TOTAL, stream>>>(x, fm, ws, b1, b2, b3, o);
}

// Round 3
// 327.051 us; speedup vs baseline: 1.6796x; 1.6796x over previous
//
#include <hip/hip_runtime.h>

// Round 3: two-kernel split through d_ws.
//   prep_weights: pack W1/W2/W3 into bf16 A-operand fragments (transposed MLP).
//   feats_kernel: rolling-window Sobel features -> bf16 feats[px][48] + sel[px].
//   mlp_kernel:   48->128->128->16 MFMA chain; W1/W3 in VGPRs, W2 in LDS.
// ws budget: 4259840 + 96*2^20 bytes ~= 100.1 MB.

#define NPX (1u << 20)

using bf16x8 = __attribute__((ext_vector_type(8))) __bf16;
using f32x4  = __attribute__((ext_vector_type(4))) float;

__device__ __forceinline__ unsigned f2bf(float f) {
    unsigned u = __float_as_uint(f);
    u += 0x7fffu + ((u >> 16) & 1u);   // RNE; inputs finite
    return u >> 16;
}

// ---- ws layout ----
// ushort weight frags at byte 0 (ushort offsets below), sel floats at byte
// 65536, feats ushort[NPX][48] at byte 4259840 (16B aligned).
#define WS1_OFF 0        // [mt=8][kb=2][lane=64][8]  A-frags of W1^T (K-pad 48->64)
#define WS2_OFF 8192     // [mt=8][kb=4][lane=64][8]  A-frags of W2^T
#define WS3_OFF 24576    // [kb=4][lane=64][8]        A-frags of W3^T
#define SEL_BYTE_OFF   65536
#define FEATS_BYTE_OFF 4259840

__global__ __launch_bounds__(1024)
void prep_weights(const float* __restrict__ w1, const float* __restrict__ w2,
                  const float* __restrict__ w3, unsigned short* __restrict__ ws) {
    const int s = threadIdx.x;           // 1024 threads, 1 block
    {   // ws1: 1024 slots  (feature order k = 3*c + t; w1 row = t*16 + c)
        const int mt = s >> 7, kb = (s >> 6) & 1, lane = s & 63;
        const int q = lane >> 4, ln = lane & 15;
#pragma unroll
        for (int j = 0; j < 8; ++j) {
            const int k = kb * 32 + q * 8 + j;
            float val = 0.f;
            if (k < 48) { const int c = k / 3, t = k - 3 * c; val = w1[(t * 16 + c) * 128 + mt * 16 + ln]; }
            ws[WS1_OFF + s * 8 + j] = (unsigned short)f2bf(val);
        }
    }
    for (int s2 = s; s2 < 2048; s2 += 1024) {   // ws2: 2048 slots
        const int mt = s2 >> 8, kb = (s2 >> 6) & 3, lane = s2 & 63;
        const int q = lane >> 4, ln = lane & 15;
#pragma unroll
        for (int j = 0; j < 8; ++j) {
            const int k = kb * 32 + q * 8 + j;
            ws[WS2_OFF + s2 * 8 + j] = (unsigned short)f2bf(w2[k * 128 + mt * 16 + ln]);
        }
    }
    if (s < 256) {   // ws3: 256 slots
        const int kb = s >> 6, lane = s & 63;
        const int q = lane >> 4, ln = lane & 15;
#pragma unroll
        for (int j = 0; j < 8; ++j) {
            const int k = kb * 32 + q * 8 + j;
            ws[WS3_OFF + s * 8 + j] = (unsigned short)f2bf(w3[k * 16 + ln]);
        }
    }
}

// ===================== kernel 1: features + sel =====================
// 512 blocks = 16 batches x 32 strips of 8 rows; 256 threads (thread = column).
#define XS_W 260   // 256 cols + pad; row start stays 16B aligned (260*4 % 16 == 0)

extern "C" __global__ __launch_bounds__(256, 3)
void feats_kernel(const float* __restrict__ x, const float* __restrict__ fmask,
                  float* __restrict__ sel, unsigned short* __restrict__ feats) {
    __shared__ float xs[3][16][XS_W];
    const int t  = threadIdx.x;
    const int bb = blockIdx.x >> 5;
    const int h0 = (blockIdx.x & 31) << 3;
    const float* xb = x + ((size_t)bb << 20);

#define LOAD_ROW(r, s) do {                                                    \
    _Pragma("unroll")                                                          \
    for (int i = 0; i < 4; ++i) {                                              \
        int idx = t + i * 256;                                                 \
        int c = idx >> 6;                                                      \
        int c4 = (idx & 63) << 2;                                              \
        float4 v = make_float4(0.f, 0.f, 0.f, 0.f);                            \
        if ((unsigned)(r) < 256u)                                              \
            v = *(const float4*)(xb + ((size_t)c << 16) + (r) * 256 + c4);     \
        *(float4*)&xs[s][c][c4] = v;                                           \
    } } while (0)

    LOAD_ROW(h0 - 1, (h0 + 2) % 3);
    LOAD_ROW(h0,      h0 % 3);

    const int col = t;
    const int cL = (col > 0)   ? col - 1 : 0;
    const int cR = (col < 255) ? col + 1 : 255;
    const float mL = (col > 0)   ? 1.f : 0.f;
    const float mR = (col < 255) ? 1.f : 0.f;

    for (int rr = 0; rr < 8; ++rr) {
        const int r = h0 + rr;
        LOAD_ROW(r + 1, (r + 1) % 3);
        __syncthreads();   // next row staged; all three slots valid
        const int sT = (r + 2) % 3, sC = r % 3, sB = (r + 1) % 3;
        unsigned pk[24];
        unsigned carry = 0;
        float selv = 0.f;
#pragma unroll
        for (int c = 0; c < 16; ++c) {
            const float* rT = xs[sT][c];
            const float* rC = xs[sC][c];
            const float* rB = xs[sB][c];
            // vertical zero-pad via zero-filled slots; horizontal via mL/mR
            const float v00 = rT[cL] * mL, v01 = rT[col], v02 = rT[cR] * mR;
            const float v10 = rC[cL] * mL, v11 = rC[col], v12 = rC[cR] * mR;
            const float v20 = rB[cL] * mL, v21 = rB[col], v22 = rB[cR] * mR;
            const float sx = (v02 + 2.f * v12 + v22) - (v00 + 2.f * v10 + v20);
            const float sy = (v20 + 2.f * v21 + v22) - (v00 + 2.f * v01 + v02);
            if (c == 3) {   // exact fp32 3x3 maxpool of alpha (x >= 0 -> zero-pad safe)
                float mx = fmaxf(fmaxf(fmaxf(v00, v01), fmaxf(v02, v10)),
                                 fmaxf(fmaxf(v11, v12), fmaxf(fmaxf(v20, v21), v22)));
                selv = (mx > 0.1f) ? 1.f : 0.f;
            }
            const unsigned ux = f2bf(v11), usx = f2bf(sx), usy = f2bf(sy);
            if ((c & 1) == 0) { pk[(c >> 1) * 3] = ux | (usx << 16); carry = usy; }
            else { pk[(c >> 1) * 3 + 1] = carry | (ux << 16);
                   pk[(c >> 1) * 3 + 2] = usx | (usy << 16); }
        }
        const size_t px = ((size_t)(bb * 256 + r) << 8) + col;
        const float fv = fmask[px];
        sel[px] = (fv != 0.f) ? selv : 0.f;
        uint4* dst = (uint4*)(feats + px * 48);
#pragma unroll
        for (int j = 0; j < 6; ++j)
            dst[j] = make_uint4(pk[j * 4 + 0], pk[j * 4 + 1], pk[j * 4 + 2], pk[j * 4 + 3]);
        __syncthreads();   // compute done before slot sT is overwritten
    }
#undef LOAD_ROW
}

// ===================== kernel 2: MLP chain =====================
// 1024 blocks x 256 thr (4 waves); wave tile = 64 px, 4 tiles/wave.
// LDS: W2 frags 32 KB (block-shared) + per-wave H1/H2 (4 KB each, xor-swizzled).
#define H_SWZ(j, ln) ((((j) ^ ((ln) & 7)) << 4))

extern "C" __global__ __launch_bounds__(256, 2)
void mlp_kernel(const unsigned short* __restrict__ wf,
                const unsigned short* __restrict__ feats,
                const float* __restrict__ sel,
                const float* __restrict__ b1, const float* __restrict__ b2,
                const float* __restrict__ b3, float* __restrict__ out) {
    extern __shared__ char smem[];
    const int t = threadIdx.x;
    const int wv = t >> 6;
    const int lane = t & 63;
    const int q = lane >> 4, ln = lane & 15;
    char* W2L = smem;                              // 32768 B
    char* H1  = smem + 32768 + wv * 8192;          // 4096 B per wave
    char* H2  = H1 + 4096;

    // stage W2 frags into LDS (block-shared), coalesced
    {
        const uint4* src = (const uint4*)(wf + WS2_OFF);
        uint4* dst = (uint4*)W2L;
#pragma unroll
        for (int i = 0; i < 8; ++i) dst[t + i * 256] = src[t + i * 256];
    }
    // W1/W3 frags -> VGPRs (80 regs total; low pressure so they stay resident)
    bf16x8 W1f[8][2], W3f[4];
#pragma unroll
    for (int mt = 0; mt < 8; ++mt) {
        W1f[mt][0] = *(const bf16x8*)(wf + WS1_OFF + ((mt * 2 + 0) * 64 + lane) * 8);
        W1f[mt][1] = *(const bf16x8*)(wf + WS1_OFF + ((mt * 2 + 1) * 64 + lane) * 8);
    }
#pragma unroll
    for (int kb = 0; kb < 4; ++kb)
        W3f[kb] = *(const bf16x8*)(wf + WS3_OFF + (kb * 64 + lane) * 8);
    __syncthreads();   // W2L ready; the only barrier

    for (int it = 0; it < 4; ++it) {
        const int tile = (blockIdx.x * 4 + wv) * 4 + it;
        const int px0 = tile << 6;
#pragma unroll
        for (int sub = 0; sub < 4; ++sub) {
            const int pxl = px0 + sub * 16 + ln;   // this lane's pixel (B-frag col)
            // ---- B-frags for layer 1 straight from feats (px-major, contiguous) ----
            const unsigned short* fp = feats + (size_t)pxl * 48;
            const bf16x8 Bk0 = *(const bf16x8*)(fp + q * 8);         // k = q*8..+7
            bf16x8 Bk1 = {};
            if (q < 2) Bk1 = *(const bf16x8*)(fp + 32 + q * 8);      // k = 32..47; 48..63 zero
            // ---- layer 1: H1^T = relu(W1^T F^T + b1) ----
#pragma unroll
            for (int mt = 0; mt < 8; ++mt) {
                f32x4 acc = *(const f32x4*)(b1 + mt * 16 + q * 4);
                acc = __builtin_amdgcn_mfma_f32_16x16x32_bf16(W1f[mt][0], Bk0, acc, 0, 0, 0);
                acc = __builtin_amdgcn_mfma_f32_16x16x32_bf16(W1f[mt][1], Bk1, acc, 0, 0, 0);
                const unsigned r01 = f2bf(fmaxf(acc[0], 0.f)) | (f2bf(fmaxf(acc[1], 0.f)) << 16);
                const unsigned r23 = f2bf(fmaxf(acc[2], 0.f)) | (f2bf(fmaxf(acc[3], 0.f)) << 16);
                *(uint2*)(H1 + ln * 256 + H_SWZ(mt * 2 + (q >> 1), ln) + ((q & 1) << 3))
                    = make_uint2(r01, r23);
            }
            bf16x8 B2[4];
#pragma unroll
            for (int kb = 0; kb < 4; ++kb)
                B2[kb] = *(const bf16x8*)(H1 + ln * 256 + H_SWZ(kb * 4 + q, ln));
            // ---- layer 2: H2^T = relu(W2^T H1^T + b2), W2 A-frags from LDS ----
#pragma unroll
            for (int mt = 0; mt < 8; ++mt) {
                f32x4 acc = *(const f32x4*)(b2 + mt * 16 + q * 4);
#pragma unroll
                for (int kb = 0; kb < 4; ++kb) {
                    const bf16x8 Af = *(const bf16x8*)(W2L + ((mt * 4 + kb) * 64 + lane) * 16);
                    acc = __builtin_amdgcn_mfma_f32_16x16x32_bf16(Af, B2[kb], acc, 0, 0, 0);
                }
                const unsigned r01 = f2bf(fmaxf(acc[0], 0.f)) | (f2bf(fmaxf(acc[1], 0.f)) << 16);
                const unsigned r23 = f2bf(fmaxf(acc[2], 0.f)) | (f2bf(fmaxf(acc[3], 0.f)) << 16);
                *(uint2*)(H2 + ln * 256 + H_SWZ(mt * 2 + (q >> 1), ln) + ((q & 1) << 3))
                    = make_uint2(r01, r23);
            }
            // ---- layer 3: U^T = W3^T H2^T + b3 ----
            f32x4 acc3 = *(const f32x4*)(b3 + q * 4);
#pragma unroll
            for (int kb = 0; kb < 4; ++kb) {
                const bf16x8 B3 = *(const bf16x8*)(H2 + ln * 256 + H_SWZ(kb * 4 + q, ln));
                acc3 = __builtin_amdgcn_mfma_f32_16x16x32_bf16(W3f[kb], B3, acc3, 0, 0, 0);
            }
            // ---- epilogue: mask + store (lane: pixel ln, channels q*4+r) ----
            const float sv = sel[pxl];
            const int bb = px0 >> 16;
            const int hw = (px0 & 65535) + sub * 16 + ln;
            float* ob = out + (((size_t)(bb * 16 + q * 4)) << 16) + hw;
#pragma unroll
            for (int r = 0; r < 4; ++r)
                ob[(size_t)r << 16] = acc3[r] * sv;
        }
    }
}

extern "C" void kernel_launch(void* const* d_in, const int* in_sizes, int n_in,
                              void* d_out, int out_size, void* d_ws, size_t ws_size,
                              hipStream_t stream) {
    (void)in_sizes; (void)n_in; (void)out_size; (void)ws_size;
    const float* x  = (const float*)d_in[0];
    const float* fm = (const float*)d_in[1];
    const float* w1 = (const float*)d_in[2];
    const float* b1 = (const float*)d_in[3];
    const float* w2 = (const float*)d_in[4];
    const float* b2 = (const float*)d_in[5];
    const float* w3 = (const float*)d_in[6];
    const float* b3 = (const float*)d_in[7];
    float* o = (float*)d_out;
    unsigned short* ws = (unsigned short*)d_ws;
    float* selbuf = (float*)((char*)d_ws + SEL_BYTE_OFF);
    unsigned short* featsbuf = (unsigned short*)((char*)d_ws + FEATS_BYTE_OFF);

    prep_weights<<<dim3(1), dim3(1024), 0, stream>>>(w1, w2, w3, ws);
    feats_kernel<<<dim3(512), dim3(256), 0, stream>>>(x, fm, selbuf, featsbuf);

    hipFuncSetAttribute((const void*)mlp_kernel,
                        hipFuncAttributeMaxDynamicSharedMemorySize, 65536);
    mlp_kernel<<<dim3(1024), dim3(256), 65536, stream>>>(ws, featsbuf, selbuf,
                                                         b1, b2, b3, o);
}